// Round 7
// baseline (1067.834 us; speedup 1.0000x reference)
//
#include <hip/hip_runtime.h>
#include <cfloat>
#include <cmath>

#define NN 40000
#define DIN 3000
#define NE 640000
#define ET (NE + NN)   // edges incl. self-loops = 680000

#define ROWS 32       // rows per block in k_enc0
#define KC 120        // K per LDS chunk (25 chunks)
#define SXX 124       // xt stride: quad=(rg*31+s)%8, 31 odd -> conflict-free
#define NF4 960       // float4 per chunk for x (32*30) and w (120*8)

__device__ __forceinline__ float lrelu(float x) { return x >= 0.f ? x : 0.2f * x; }
__device__ __forceinline__ float elu(float x)   { return x > 0.f ? x : expm1f(x); }

// ---------------- Kernel A: h = elu(bn(x @ e0_w + e0_b)) ----------------
// 32 rows x 32 cols per block; thread = 1 row x 4 cols (acc = 1 float4).
// Per 120-k chunk: stage x[32][120] (stride 124, conflict-free) + w[120][32]
// in LDS. T14 async split: issue chunk+1 global loads BEFORE computing chunk,
// ds_write after barrier -> HBM latency hides under compute.
__global__ __launch_bounds__(256) void k_enc0(
    const float* __restrict__ x, const float* __restrict__ w,
    const float* __restrict__ b, const float* __restrict__ g,
    const float* __restrict__ beta, const float* __restrict__ m,
    const float* __restrict__ v, float* __restrict__ h)
{
    __shared__ float xt[ROWS * SXX];   // 15.9 KB
    __shared__ float wt[KC * 32];      // 15.4 KB
    const int tid = threadIdx.x;
    const int cg = tid & 7;            // 4-col group
    const int rg = tid >> 3;           // row 0..31
    const int row0 = blockIdx.x * ROWS;

    // per-thread staging assignment (4 slots, last partially used: 960/256=3.75)
    int si[4], sr[4], sq[4];
    #pragma unroll
    for (int t = 0; t < 4; t++) {
        int i = tid + t * 256;
        si[t] = i;
        sr[t] = i / 30;                // x row
        sq[t] = i - sr[t] * 30;        // x quad within row
    }

    float4 acc = make_float4(0.f, 0.f, 0.f, 0.f);
    float4 xr[4], wr4[4];

    // prologue: load + write chunk 0
    #pragma unroll
    for (int t = 0; t < 4; t++) {
        if (si[t] < NF4) {
            xr[t] = *(const float4*)&x[(size_t)(row0 + sr[t]) * DIN + sq[t] * 4];
            wr4[t] = ((const float4*)w)[si[t]];
        }
    }
    #pragma unroll
    for (int t = 0; t < 4; t++) {
        if (si[t] < NF4) {
            *(float4*)&xt[sr[t] * SXX + sq[t] * 4] = xr[t];
            ((float4*)wt)[si[t]] = wr4[t];
        }
    }
    __syncthreads();

    for (int ch = 0; ch < DIN / KC; ch++) {
        // issue next chunk's loads (latency hidden under compute below)
        if (ch < DIN / KC - 1) {
            const int kc = (ch + 1) * KC;
            #pragma unroll
            for (int t = 0; t < 4; t++) {
                if (si[t] < NF4) {
                    xr[t] = *(const float4*)&x[(size_t)(row0 + sr[t]) * DIN + kc + sq[t] * 4];
                    wr4[t] = ((const float4*)&w[(size_t)kc * 32])[si[t]];
                }
            }
        }
        // compute current chunk: 30 x 4-k steps
        #pragma unroll 6
        for (int s = 0; s < KC / 4; s++) {
            float4 xa = *(const float4*)&xt[rg * SXX + s * 4];
            #pragma unroll
            for (int i = 0; i < 4; i++) {
                float4 wv = *(const float4*)&wt[(s * 4 + i) * 32 + cg * 4];
                float xs = (i == 0) ? xa.x : (i == 1) ? xa.y : (i == 2) ? xa.z : xa.w;
                acc.x += xs * wv.x;
                acc.y += xs * wv.y;
                acc.z += xs * wv.z;
                acc.w += xs * wv.w;
            }
        }
        __syncthreads();   // all waves done reading current LDS
        if (ch < DIN / KC - 1) {
            #pragma unroll
            for (int t = 0; t < 4; t++) {
                if (si[t] < NF4) {
                    *(float4*)&xt[sr[t] * SXX + sq[t] * 4] = xr[t];
                    ((float4*)wt)[si[t]] = wr4[t];
                }
            }
        }
        __syncthreads();
    }

    // fused BN + ELU epilogue
    const int row = row0 + rg;
    const int c = cg * 4;
    float4 o;
    float sc0 = g[c+0] * rsqrtf(v[c+0] + 1e-3f);
    float sc1 = g[c+1] * rsqrtf(v[c+1] + 1e-3f);
    float sc2 = g[c+2] * rsqrtf(v[c+2] + 1e-3f);
    float sc3 = g[c+3] * rsqrtf(v[c+3] + 1e-3f);
    o.x = elu((acc.x + b[c+0]) * sc0 + (beta[c+0] - m[c+0] * sc0));
    o.y = elu((acc.y + b[c+1]) * sc1 + (beta[c+1] - m[c+1] * sc1));
    o.z = elu((acc.z + b[c+2]) * sc2 + (beta[c+2] - m[c+2] * sc2));
    o.w = elu((acc.w + b[c+3]) * sc3 + (beta[c+3] - m[c+3] * sc3));
    *(float4*)&h[(size_t)row * 32 + c] = o;
}

// ------------- Kernel B: feat_x, hw1, attention scalars, init GAT1 atomics -------------
__global__ void k_enc1_prep(
    const float* __restrict__ h,
    const float* __restrict__ e1w, const float* __restrict__ e1b,
    const float* __restrict__ e1g, const float* __restrict__ e1beta,
    const float* __restrict__ e1m, const float* __restrict__ e1v,
    const float* __restrict__ g1w, const float* __restrict__ g1as,
    const float* __restrict__ g1ad,
    float* __restrict__ out_fx, float* __restrict__ hw1,
    float* __restrict__ s1src, float* __restrict__ s1dst,
    float* __restrict__ z1, float* __restrict__ acc1)
{
    int row = blockIdx.x * 256 + threadIdx.x;
    if (row >= NN) return;
    float hr[32];
    #pragma unroll
    for (int k = 0; k < 32; k++) hr[k] = h[(size_t)row * 32 + k];
    float fx[20];
    for (int c = 0; c < 20; c++) {
        float s = e1b[c];
        for (int k = 0; k < 32; k++) s += hr[k] * e1w[k * 20 + c];
        float sc = e1g[c] * rsqrtf(e1v[c] + 1e-3f);
        s = (s - e1m[c]) * sc + e1beta[c];
        fx[c] = elu(s);
        out_fx[(size_t)row * 20 + c] = fx[c];
    }
    float ss = 0.f, sd = 0.f;
    for (int c = 0; c < 64; c++) {
        float s = 0.f;
        for (int k = 0; k < 20; k++) s += fx[k] * g1w[k * 64 + c];
        hw1[(size_t)row * 64 + c] = s;
        ss += s * g1as[c];
        sd += s * g1ad[c];
        acc1[(size_t)row * 64 + c] = 0.f;
    }
    s1src[row] = ss; s1dst[row] = sd;
    z1[row] = 0.f;
}

// ------------- Kernel D: GAT1 numerator/denominator accumulate (64 lanes/edge) -------------
// softmax is shift-invariant: use exp(al) directly (logits bounded ~|3|), skip max pass.
__global__ __launch_bounds__(256) void k_gat1_acc(const int* __restrict__ ei,
    const float* __restrict__ s1src, const float* __restrict__ s1dst,
    const float* __restrict__ hw1,
    float* __restrict__ z1, float* __restrict__ acc1)
{
    int t = blockIdx.x * 256 + threadIdx.x;
    int lane = t & 63;
    int e = t >> 6;
    if (e >= ET) return;
    int s, d;
    if (e < NE) { s = ei[e]; d = ei[NE + e]; } else { s = d = e - NE; }
    float al = lrelu(s1src[s] + s1dst[d]);
    float ex = expf(al);
    if (lane == 0) atomicAdd(&z1[d], ex);
    atomicAdd(&acc1[(size_t)d * 64 + lane], ex * hw1[(size_t)s * 64 + lane]);
}

// ------------- Kernel E: normalize GAT1, BN+ReLU -> c; hw_m/hw_v + scalars; init atomics -------------
__global__ void k_gat1_norm(
    const float* __restrict__ acc1, const float* __restrict__ z1,
    const float* __restrict__ g1b,
    const float* __restrict__ bncg, const float* __restrict__ bncbeta,
    const float* __restrict__ bncm, const float* __restrict__ bncv,
    const float* __restrict__ gmw, const float* __restrict__ gmas, const float* __restrict__ gmad,
    const float* __restrict__ gvw, const float* __restrict__ gvas, const float* __restrict__ gvad,
    float* __restrict__ hwm, float* __restrict__ hwv,
    float* __restrict__ smsrc, float* __restrict__ smdst,
    float* __restrict__ svsrc, float* __restrict__ svdst,
    float* __restrict__ zm, float* __restrict__ zv,
    float* __restrict__ accm, float* __restrict__ accv)
{
    int row = blockIdx.x * 256 + threadIdx.x;
    if (row >= NN) return;
    float zi = 1.f / (z1[row] + 1e-16f);
    float c[64];
    for (int f = 0; f < 64; f++) {
        float val = acc1[(size_t)row * 64 + f] * zi + g1b[f];
        float sc = bncg[f] * rsqrtf(bncv[f] + 1e-5f);
        val = (val - bncm[f]) * sc + bncbeta[f];
        c[f] = val > 0.f ? val : 0.f;
    }
    float ssm = 0.f, sdm = 0.f, ssv = 0.f, sdv = 0.f;
    for (int o = 0; o < 8; o++) {
        float sm = 0.f, sv = 0.f;
        for (int k = 0; k < 64; k++) {
            sm += c[k] * gmw[k * 8 + o];
            sv += c[k] * gvw[k * 8 + o];
        }
        hwm[(size_t)row * 8 + o] = sm; hwv[(size_t)row * 8 + o] = sv;
        ssm += sm * gmas[o]; sdm += sm * gmad[o];
        ssv += sv * gvas[o]; sdv += sv * gvad[o];
        accm[(size_t)row * 8 + o] = 0.f; accv[(size_t)row * 8 + o] = 0.f;
    }
    smsrc[row] = ssm; smdst[row] = sdm;
    svsrc[row] = ssv; svdst[row] = sdv;
    zm[row] = 0.f;
    zv[row] = 0.f;
}

// ------------- Kernel G: mu/logvar GAT accumulate (8 lanes/edge), no max pass -------------
__global__ __launch_bounds__(256) void k_gat23_acc(const int* __restrict__ ei,
    const float* __restrict__ smsrc, const float* __restrict__ smdst,
    const float* __restrict__ svsrc, const float* __restrict__ svdst,
    const float* __restrict__ hwm, const float* __restrict__ hwv,
    float* __restrict__ zm, float* __restrict__ accm,
    float* __restrict__ zv, float* __restrict__ accv)
{
    int t = blockIdx.x * 256 + threadIdx.x;
    int lane = t & 7;
    int e = t >> 3;
    if (e >= ET) return;
    int s, d;
    if (e < NE) { s = ei[e]; d = ei[NE + e]; } else { s = d = e - NE; }
    float am = lrelu(smsrc[s] + smdst[d]);
    float exm = expf(am);
    if (lane == 0) atomicAdd(&zm[d], exm);
    atomicAdd(&accm[(size_t)d * 8 + lane], exm * hwm[(size_t)s * 8 + lane]);
    float av = lrelu(svsrc[s] + svdst[d]);
    float exv = expf(av);
    if (lane == 0) atomicAdd(&zv[d], exv);
    atomicAdd(&accv[(size_t)d * 8 + lane], exv * hwv[(size_t)s * 8 + lane]);
}

// ------------- Kernel H: mu/logvar/gnn_z/z, decoder L0, student-t q -------------
__global__ void k_final(
    const float* __restrict__ accm, const float* __restrict__ zm, const float* __restrict__ gmb,
    const float* __restrict__ accv, const float* __restrict__ zv, const float* __restrict__ gvb,
    const float* __restrict__ epsin, const float* __restrict__ fx_out,
    const float* __restrict__ d0w, const float* __restrict__ d0b,
    const float* __restrict__ d0g, const float* __restrict__ d0beta,
    const float* __restrict__ d0m, const float* __restrict__ d0v,
    const float* __restrict__ cluster,
    float* __restrict__ out_z, float* __restrict__ out_mu, float* __restrict__ out_lv,
    float* __restrict__ out_q, float* __restrict__ out_gz, float* __restrict__ dbuf)
{
    int row = blockIdx.x * 256 + threadIdx.x;
    if (row >= NN) return;
    float zvec[28];
    #pragma unroll
    for (int k = 0; k < 20; k++) zvec[k] = fx_out[(size_t)row * 20 + k];
    float zim = 1.f / (zm[row] + 1e-16f);
    float ziv = 1.f / (zv[row] + 1e-16f);
    #pragma unroll
    for (int o = 0; o < 8; o++) {
        float mu = accm[(size_t)row * 8 + o] * zim + gmb[o];
        float lv = accv[(size_t)row * 8 + o] * ziv + gvb[o];
        float gz = epsin[(size_t)row * 8 + o] * expf(lv) + mu;
        out_mu[(size_t)row * 8 + o] = mu;
        out_lv[(size_t)row * 8 + o] = lv;
        out_gz[(size_t)row * 8 + o] = gz;
        zvec[20 + o] = gz;
    }
    #pragma unroll
    for (int k = 0; k < 28; k++) out_z[(size_t)row * 28 + k] = zvec[k];
    // decoder L0: elu(bn(z @ d0_w + d0_b))
    for (int c = 0; c < 32; c++) {
        float s = d0b[c];
        for (int k = 0; k < 28; k++) s += zvec[k] * d0w[k * 32 + c];
        float sc = d0g[c] * rsqrtf(d0v[c] + 1e-3f);
        s = (s - d0m[c]) * sc + d0beta[c];
        dbuf[(size_t)row * 32 + c] = elu(s);
    }
    // student-t q
    float zz = 0.f;
    #pragma unroll
    for (int k = 0; k < 28; k++) zz += zvec[k] * zvec[k];
    float qv[15], qs = 0.f;
    for (int j = 0; j < 15; j++) {
        float cc = 0.f, zc = 0.f;
        for (int k = 0; k < 28; k++) {
            float cv = cluster[j * 28 + k];
            cc += cv * cv; zc += zvec[k] * cv;
        }
        float sq = zz + cc - 2.f * zc;
        if (sq < 0.f) sq = 0.f;
        float qb = 1.f / (1.f + sq * (1.f / 0.9f) + 1e-8f);
        qb = powf(qb, 0.95f);
        qv[j] = qb; qs += qb;
    }
    float qi = 1.f / qs;
    #pragma unroll
    for (int j = 0; j < 15; j++) out_q[(size_t)row * 15 + j] = qv[j] * qi;
}

// ------------- Kernel I: de_feat = d @ out_w + out_b -------------
#define DQ 750   // DIN/4 quads per row
__global__ __launch_bounds__(256) void k_dec_out(
    const float* __restrict__ dbuf, const float* __restrict__ ow,
    const float* __restrict__ ob, float* __restrict__ out_de)
{
    __shared__ float4 wt[32 * 64];   // [k][quad]
    __shared__ float  dt[64 * 32];   // [row][k]
    const int tid = threadIdx.x;
    const int cq0 = blockIdx.x * 64;      // quad base in output row
    const int row0 = blockIdx.y * 64;

    // load w tile: 32 k-rows x 64 quads
    #pragma unroll
    for (int i = 0; i < 8; i++) {
        int t = tid + i * 256;            // 0..2047
        int k = t >> 6, lq = t & 63;
        int gq = cq0 + lq;
        wt[t] = (gq < DQ) ? ((const float4*)ow)[(size_t)k * DQ + gq]
                          : make_float4(0.f, 0.f, 0.f, 0.f);
    }
    // load d tile: 64 rows x 32 = 512 float4
    #pragma unroll
    for (int i = 0; i < 2; i++) {
        int t = tid + i * 256;
        ((float4*)dt)[t] = ((const float4*)dbuf)[(size_t)row0 * 8 + t];
    }
    __syncthreads();

    const int qid = tid & 63;
    const int rg  = tid >> 6;             // wave-uniform row group (0..3)
    const int q   = cq0 + qid;
    const bool valid = q < DQ;

    float4 acc[16];
    #pragma unroll
    for (int r = 0; r < 16; r++) acc[r] = make_float4(0.f, 0.f, 0.f, 0.f);

    #pragma unroll
    for (int k4 = 0; k4 < 8; k4++) {
        float4 w0 = wt[(k4 * 4 + 0) * 64 + qid];
        float4 w1 = wt[(k4 * 4 + 1) * 64 + qid];
        float4 w2 = wt[(k4 * 4 + 2) * 64 + qid];
        float4 w3 = wt[(k4 * 4 + 3) * 64 + qid];
        #pragma unroll
        for (int r = 0; r < 16; r++) {
            float4 dq = *(const float4*)&dt[(rg * 16 + r) * 32 + k4 * 4]; // broadcast
            acc[r].x += dq.x * w0.x; acc[r].y += dq.x * w0.y;
            acc[r].z += dq.x * w0.z; acc[r].w += dq.x * w0.w;
            acc[r].x += dq.y * w1.x; acc[r].y += dq.y * w1.y;
            acc[r].z += dq.y * w1.z; acc[r].w += dq.y * w1.w;
            acc[r].x += dq.z * w2.x; acc[r].y += dq.z * w2.y;
            acc[r].z += dq.z * w2.z; acc[r].w += dq.z * w2.w;
            acc[r].x += dq.w * w3.x; acc[r].y += dq.w * w3.y;
            acc[r].z += dq.w * w3.z; acc[r].w += dq.w * w3.w;
        }
    }

    if (valid) {
        float4 bq = ((const float4*)ob)[q];
        #pragma unroll
        for (int r = 0; r < 16; r++) {
            float4 o;
            o.x = acc[r].x + bq.x; o.y = acc[r].y + bq.y;
            o.z = acc[r].z + bq.z; o.w = acc[r].w + bq.w;
            ((float4*)out_de)[(size_t)(row0 + rg * 16 + r) * DQ + q] = o;
        }
    }
}

extern "C" void kernel_launch(void* const* d_in, const int* in_sizes, int n_in,
                              void* d_out, int out_size, void* d_ws, size_t ws_size,
                              hipStream_t stream) {
    const float* x      = (const float*)d_in[0];
    const int*   ei     = (const int*)  d_in[1];
    const float* e0_w   = (const float*)d_in[2];
    const float* e0_b   = (const float*)d_in[3];
    const float* e0_g   = (const float*)d_in[4];
    const float* e0_be  = (const float*)d_in[5];
    const float* e0_m   = (const float*)d_in[6];
    const float* e0_v   = (const float*)d_in[7];
    const float* e1_w   = (const float*)d_in[8];
    const float* e1_b   = (const float*)d_in[9];
    const float* e1_g   = (const float*)d_in[10];
    const float* e1_be  = (const float*)d_in[11];
    const float* e1_m   = (const float*)d_in[12];
    const float* e1_v   = (const float*)d_in[13];
    const float* g1_w   = (const float*)d_in[14];
    const float* g1_as  = (const float*)d_in[15];
    const float* g1_ad  = (const float*)d_in[16];
    const float* g1_b   = (const float*)d_in[17];
    const float* bnc_g  = (const float*)d_in[18];
    const float* bnc_be = (const float*)d_in[19];
    const float* bnc_m  = (const float*)d_in[20];
    const float* bnc_v  = (const float*)d_in[21];
    const float* gm_w   = (const float*)d_in[22];
    const float* gm_as  = (const float*)d_in[23];
    const float* gm_ad  = (const float*)d_in[24];
    const float* gm_b   = (const float*)d_in[25];
    const float* gv_w   = (const float*)d_in[26];
    const float* gv_as  = (const float*)d_in[27];
    const float* gv_ad  = (const float*)d_in[28];
    const float* gv_b   = (const float*)d_in[29];
    const float* d0_w   = (const float*)d_in[30];
    const float* d0_b   = (const float*)d_in[31];
    const float* d0_g   = (const float*)d_in[32];
    const float* d0_be  = (const float*)d_in[33];
    const float* d0_m   = (const float*)d_in[34];
    const float* d0_v   = (const float*)d_in[35];
    const float* out_w  = (const float*)d_in[36];
    const float* out_b  = (const float*)d_in[37];
    const float* cluster= (const float*)d_in[38];
    const float* epsin  = (const float*)d_in[39];

    float* out = (float*)d_out;
    // output offsets (floats), return order: z, mu, logvar, de_feat, q, feat_x, gnn_z
    float* out_z  = out;
    float* out_mu = out + (size_t)NN * 28;
    float* out_lv = out + (size_t)NN * 36;
    float* out_de = out + (size_t)NN * 44;
    float* out_q  = out + (size_t)NN * 44 + (size_t)NN * DIN;
    float* out_fx = out + (size_t)NN * 59 + (size_t)NN * DIN;
    float* out_gz = out + (size_t)NN * 79 + (size_t)NN * DIN;

    float* ws = (float*)d_ws;
    const size_t n = NN;
    // phase-1 layout
    float* hw1   = ws;                 // 64N
    float* acc1  = ws + 64 * n;        // 64N
    float* hbuf  = ws + 128 * n;       // 32N (h, later reused as dbuf)
    float* s1src = ws + 160 * n;
    float* s1dst = ws + 161 * n;
    float* z1    = ws + 162 * n;
    // phase-2 layout (reuses hw1's 64N block after GAT1 is done)
    float* hwm   = ws;                 // 8N
    float* hwv   = ws + 8 * n;         // 8N
    float* smsrc = ws + 16 * n;
    float* smdst = ws + 17 * n;
    float* svsrc = ws + 18 * n;
    float* svdst = ws + 19 * n;
    float* zm    = ws + 20 * n;
    float* zv    = ws + 21 * n;
    float* accm  = ws + 24 * n;        // 8N
    float* accv  = ws + 32 * n;        // 8N
    float* dbuf  = hbuf;               // 32N

    const int NB_ROWS = (NN + 255) / 256;  // 157

    k_enc0<<<NN / ROWS, 256, 0, stream>>>(x, e0_w, e0_b, e0_g, e0_be, e0_m, e0_v, hbuf);
    k_enc1_prep<<<NB_ROWS, 256, 0, stream>>>(hbuf, e1_w, e1_b, e1_g, e1_be, e1_m, e1_v,
                                             g1_w, g1_as, g1_ad,
                                             out_fx, hw1, s1src, s1dst, z1, acc1);
    k_gat1_acc<<<(ET * 64) / 256, 256, 0, stream>>>(ei, s1src, s1dst, hw1, z1, acc1);
    k_gat1_norm<<<NB_ROWS, 256, 0, stream>>>(acc1, z1, g1_b, bnc_g, bnc_be, bnc_m, bnc_v,
                                             gm_w, gm_as, gm_ad, gv_w, gv_as, gv_ad,
                                             hwm, hwv, smsrc, smdst, svsrc, svdst,
                                             zm, zv, accm, accv);
    k_gat23_acc<<<(ET * 8) / 256, 256, 0, stream>>>(ei, smsrc, smdst, svsrc, svdst,
                                                    hwm, hwv, zm, accm, zv, accv);
    k_final<<<NB_ROWS, 256, 0, stream>>>(accm, zm, gm_b, accv, zv, gv_b, epsin, out_fx,
                                         d0_w, d0_b, d0_g, d0_be, d0_m, d0_v, cluster,
                                         out_z, out_mu, out_lv, out_q, out_gz, dbuf);
    dim3 dec_grid((DQ + 63) / 64, NN / 64);
    k_dec_out<<<dec_grid, 256, 0, stream>>>(dbuf, out_w, out_b, out_de);
}

// Round 8
// 1067.088 us; speedup vs baseline: 1.0007x; 1.0007x over previous
//
#include <hip/hip_runtime.h>
#include <cfloat>
#include <cmath>

#define NN 40000
#define DIN 3000
#define NE 640000
#define ET (NE + NN)   // edges incl. self-loops = 680000

#define ROWS 32       // rows per block in k_enc0
#define KC 120        // K per LDS chunk (25 chunks)
#define SXX 124       // xt stride: words rg*124%32 step -4 -> 8 rows hit 32 distinct banks
#define NF4 960       // float4 per chunk for x (32*30) and w (120*8)

__device__ __forceinline__ float lrelu(float x) { return x >= 0.f ? x : 0.2f * x; }
__device__ __forceinline__ float elu(float x)   { return x > 0.f ? x : expm1f(x); }

// ---------------- Kernel A: h = elu(bn(x @ e0_w + e0_b)) ----------------
// 32 rows x 32 cols per block; thread = 1 row x 4 cols (acc = 1 float4).
// Per 120-k chunk: stage x[32][120] (stride 124, conflict-free) + w[120][32]
// in LDS. T14 async split: issue chunk+1 global loads BEFORE computing chunk,
// ds_write after barrier -> HBM latency hides under compute.
// __launch_bounds__(256,4): VGPR cap 128 so the 32-VGPR prefetch state stays
// in registers (default bounds -> 44 VGPR -> 0.9GB scratch spill, round 6).
__global__ __launch_bounds__(256, 4) void k_enc0(
    const float* __restrict__ x, const float* __restrict__ w,
    const float* __restrict__ b, const float* __restrict__ g,
    const float* __restrict__ beta, const float* __restrict__ m,
    const float* __restrict__ v, float* __restrict__ h)
{
    __shared__ float xt[ROWS * SXX];   // 15.9 KB
    __shared__ float wt[KC * 32];      // 15.4 KB
    const int tid = threadIdx.x;
    const int cg = tid & 7;            // 4-col group
    const int rg = tid >> 3;           // row 0..31
    const int row0 = blockIdx.x * ROWS;

    // per-thread staging assignment (4 slots, last partially used: 960/256=3.75)
    int si[4], sr[4], sq[4];
    #pragma unroll
    for (int t = 0; t < 4; t++) {
        int i = tid + t * 256;
        si[t] = i;
        sr[t] = i / 30;                // x row
        sq[t] = i - sr[t] * 30;        // x quad within row
    }

    float4 acc = make_float4(0.f, 0.f, 0.f, 0.f);
    float4 xr[4], wr4[4];

    // prologue: load + write chunk 0
    #pragma unroll
    for (int t = 0; t < 4; t++) {
        if (si[t] < NF4) {
            xr[t] = *(const float4*)&x[(size_t)(row0 + sr[t]) * DIN + sq[t] * 4];
            wr4[t] = ((const float4*)w)[si[t]];
        }
    }
    #pragma unroll
    for (int t = 0; t < 4; t++) {
        if (si[t] < NF4) {
            *(float4*)&xt[sr[t] * SXX + sq[t] * 4] = xr[t];
            ((float4*)wt)[si[t]] = wr4[t];
        }
    }
    __syncthreads();

    for (int ch = 0; ch < DIN / KC; ch++) {
        // issue next chunk's loads (latency hidden under compute below)
        if (ch < DIN / KC - 1) {
            const int kc = (ch + 1) * KC;
            #pragma unroll
            for (int t = 0; t < 4; t++) {
                if (si[t] < NF4) {
                    xr[t] = *(const float4*)&x[(size_t)(row0 + sr[t]) * DIN + kc + sq[t] * 4];
                    wr4[t] = ((const float4*)&w[(size_t)kc * 32])[si[t]];
                }
            }
        }
        // compute current chunk: 30 x 4-k steps
        #pragma unroll 6
        for (int s = 0; s < KC / 4; s++) {
            float4 xa = *(const float4*)&xt[rg * SXX + s * 4];
            #pragma unroll
            for (int i = 0; i < 4; i++) {
                float4 wv = *(const float4*)&wt[(s * 4 + i) * 32 + cg * 4];
                float xs = (i == 0) ? xa.x : (i == 1) ? xa.y : (i == 2) ? xa.z : xa.w;
                acc.x += xs * wv.x;
                acc.y += xs * wv.y;
                acc.z += xs * wv.z;
                acc.w += xs * wv.w;
            }
        }
        __syncthreads();   // all waves done reading current LDS
        if (ch < DIN / KC - 1) {
            #pragma unroll
            for (int t = 0; t < 4; t++) {
                if (si[t] < NF4) {
                    *(float4*)&xt[sr[t] * SXX + sq[t] * 4] = xr[t];
                    ((float4*)wt)[si[t]] = wr4[t];
                }
            }
        }
        __syncthreads();
    }

    // fused BN + ELU epilogue
    const int row = row0 + rg;
    const int c = cg * 4;
    float4 o;
    float sc0 = g[c+0] * rsqrtf(v[c+0] + 1e-3f);
    float sc1 = g[c+1] * rsqrtf(v[c+1] + 1e-3f);
    float sc2 = g[c+2] * rsqrtf(v[c+2] + 1e-3f);
    float sc3 = g[c+3] * rsqrtf(v[c+3] + 1e-3f);
    o.x = elu((acc.x + b[c+0]) * sc0 + (beta[c+0] - m[c+0] * sc0));
    o.y = elu((acc.y + b[c+1]) * sc1 + (beta[c+1] - m[c+1] * sc1));
    o.z = elu((acc.z + b[c+2]) * sc2 + (beta[c+2] - m[c+2] * sc2));
    o.w = elu((acc.w + b[c+3]) * sc3 + (beta[c+3] - m[c+3] * sc3));
    *(float4*)&h[(size_t)row * 32 + c] = o;
}

// ------------- Kernel B: feat_x, hw1, attention scalars, init GAT1 atomics -------------
__global__ void k_enc1_prep(
    const float* __restrict__ h,
    const float* __restrict__ e1w, const float* __restrict__ e1b,
    const float* __restrict__ e1g, const float* __restrict__ e1beta,
    const float* __restrict__ e1m, const float* __restrict__ e1v,
    const float* __restrict__ g1w, const float* __restrict__ g1as,
    const float* __restrict__ g1ad,
    float* __restrict__ out_fx, float* __restrict__ hw1,
    float* __restrict__ s1src, float* __restrict__ s1dst,
    float* __restrict__ z1, float* __restrict__ acc1)
{
    int row = blockIdx.x * 256 + threadIdx.x;
    if (row >= NN) return;
    float hr[32];
    #pragma unroll
    for (int k = 0; k < 32; k++) hr[k] = h[(size_t)row * 32 + k];
    float fx[20];
    for (int c = 0; c < 20; c++) {
        float s = e1b[c];
        for (int k = 0; k < 32; k++) s += hr[k] * e1w[k * 20 + c];
        float sc = e1g[c] * rsqrtf(e1v[c] + 1e-3f);
        s = (s - e1m[c]) * sc + e1beta[c];
        fx[c] = elu(s);
        out_fx[(size_t)row * 20 + c] = fx[c];
    }
    float ss = 0.f, sd = 0.f;
    for (int c = 0; c < 64; c++) {
        float s = 0.f;
        for (int k = 0; k < 20; k++) s += fx[k] * g1w[k * 64 + c];
        hw1[(size_t)row * 64 + c] = s;
        ss += s * g1as[c];
        sd += s * g1ad[c];
        acc1[(size_t)row * 64 + c] = 0.f;
    }
    s1src[row] = ss; s1dst[row] = sd;
    z1[row] = 0.f;
}

// ------------- Kernel D: GAT1 numerator/denominator accumulate (64 lanes/edge) -------------
// softmax is shift-invariant: use exp(al) directly (logits bounded ~|3|), skip max pass.
__global__ __launch_bounds__(256) void k_gat1_acc(const int* __restrict__ ei,
    const float* __restrict__ s1src, const float* __restrict__ s1dst,
    const float* __restrict__ hw1,
    float* __restrict__ z1, float* __restrict__ acc1)
{
    int t = blockIdx.x * 256 + threadIdx.x;
    int lane = t & 63;
    int e = t >> 6;
    if (e >= ET) return;
    int s, d;
    if (e < NE) { s = ei[e]; d = ei[NE + e]; } else { s = d = e - NE; }
    float al = lrelu(s1src[s] + s1dst[d]);
    float ex = expf(al);
    if (lane == 0) atomicAdd(&z1[d], ex);
    atomicAdd(&acc1[(size_t)d * 64 + lane], ex * hw1[(size_t)s * 64 + lane]);
}

// ------------- Kernel E: normalize GAT1, BN+ReLU -> c; hw_m/hw_v + scalars; init atomics -------------
__global__ void k_gat1_norm(
    const float* __restrict__ acc1, const float* __restrict__ z1,
    const float* __restrict__ g1b,
    const float* __restrict__ bncg, const float* __restrict__ bncbeta,
    const float* __restrict__ bncm, const float* __restrict__ bncv,
    const float* __restrict__ gmw, const float* __restrict__ gmas, const float* __restrict__ gmad,
    const float* __restrict__ gvw, const float* __restrict__ gvas, const float* __restrict__ gvad,
    float* __restrict__ hwm, float* __restrict__ hwv,
    float* __restrict__ smsrc, float* __restrict__ smdst,
    float* __restrict__ svsrc, float* __restrict__ svdst,
    float* __restrict__ zm, float* __restrict__ zv,
    float* __restrict__ accm, float* __restrict__ accv)
{
    int row = blockIdx.x * 256 + threadIdx.x;
    if (row >= NN) return;
    float zi = 1.f / (z1[row] + 1e-16f);
    float c[64];
    for (int f = 0; f < 64; f++) {
        float val = acc1[(size_t)row * 64 + f] * zi + g1b[f];
        float sc = bncg[f] * rsqrtf(bncv[f] + 1e-5f);
        val = (val - bncm[f]) * sc + bncbeta[f];
        c[f] = val > 0.f ? val : 0.f;
    }
    float ssm = 0.f, sdm = 0.f, ssv = 0.f, sdv = 0.f;
    for (int o = 0; o < 8; o++) {
        float sm = 0.f, sv = 0.f;
        for (int k = 0; k < 64; k++) {
            sm += c[k] * gmw[k * 8 + o];
            sv += c[k] * gvw[k * 8 + o];
        }
        hwm[(size_t)row * 8 + o] = sm; hwv[(size_t)row * 8 + o] = sv;
        ssm += sm * gmas[o]; sdm += sm * gmad[o];
        ssv += sv * gvas[o]; sdv += sv * gvad[o];
        accm[(size_t)row * 8 + o] = 0.f; accv[(size_t)row * 8 + o] = 0.f;
    }
    smsrc[row] = ssm; smdst[row] = sdm;
    svsrc[row] = ssv; svdst[row] = sdv;
    zm[row] = 0.f;
    zv[row] = 0.f;
}

// ------------- Kernel G: mu/logvar GAT accumulate (8 lanes/edge), no max pass -------------
__global__ __launch_bounds__(256) void k_gat23_acc(const int* __restrict__ ei,
    const float* __restrict__ smsrc, const float* __restrict__ smdst,
    const float* __restrict__ svsrc, const float* __restrict__ svdst,
    const float* __restrict__ hwm, const float* __restrict__ hwv,
    float* __restrict__ zm, float* __restrict__ accm,
    float* __restrict__ zv, float* __restrict__ accv)
{
    int t = blockIdx.x * 256 + threadIdx.x;
    int lane = t & 7;
    int e = t >> 3;
    if (e >= ET) return;
    int s, d;
    if (e < NE) { s = ei[e]; d = ei[NE + e]; } else { s = d = e - NE; }
    float am = lrelu(smsrc[s] + smdst[d]);
    float exm = expf(am);
    if (lane == 0) atomicAdd(&zm[d], exm);
    atomicAdd(&accm[(size_t)d * 8 + lane], exm * hwm[(size_t)s * 8 + lane]);
    float av = lrelu(svsrc[s] + svdst[d]);
    float exv = expf(av);
    if (lane == 0) atomicAdd(&zv[d], exv);
    atomicAdd(&accv[(size_t)d * 8 + lane], exv * hwv[(size_t)s * 8 + lane]);
}

// ------------- Kernel H: mu/logvar/gnn_z/z, decoder L0, student-t q -------------
__global__ void k_final(
    const float* __restrict__ accm, const float* __restrict__ zm, const float* __restrict__ gmb,
    const float* __restrict__ accv, const float* __restrict__ zv, const float* __restrict__ gvb,
    const float* __restrict__ epsin, const float* __restrict__ fx_out,
    const float* __restrict__ d0w, const float* __restrict__ d0b,
    const float* __restrict__ d0g, const float* __restrict__ d0beta,
    const float* __restrict__ d0m, const float* __restrict__ d0v,
    const float* __restrict__ cluster,
    float* __restrict__ out_z, float* __restrict__ out_mu, float* __restrict__ out_lv,
    float* __restrict__ out_q, float* __restrict__ out_gz, float* __restrict__ dbuf)
{
    int row = blockIdx.x * 256 + threadIdx.x;
    if (row >= NN) return;
    float zvec[28];
    #pragma unroll
    for (int k = 0; k < 20; k++) zvec[k] = fx_out[(size_t)row * 20 + k];
    float zim = 1.f / (zm[row] + 1e-16f);
    float ziv = 1.f / (zv[row] + 1e-16f);
    #pragma unroll
    for (int o = 0; o < 8; o++) {
        float mu = accm[(size_t)row * 8 + o] * zim + gmb[o];
        float lv = accv[(size_t)row * 8 + o] * ziv + gvb[o];
        float gz = epsin[(size_t)row * 8 + o] * expf(lv) + mu;
        out_mu[(size_t)row * 8 + o] = mu;
        out_lv[(size_t)row * 8 + o] = lv;
        out_gz[(size_t)row * 8 + o] = gz;
        zvec[20 + o] = gz;
    }
    #pragma unroll
    for (int k = 0; k < 28; k++) out_z[(size_t)row * 28 + k] = zvec[k];
    // decoder L0: elu(bn(z @ d0_w + d0_b))
    for (int c = 0; c < 32; c++) {
        float s = d0b[c];
        for (int k = 0; k < 28; k++) s += zvec[k] * d0w[k * 32 + c];
        float sc = d0g[c] * rsqrtf(d0v[c] + 1e-3f);
        s = (s - d0m[c]) * sc + d0beta[c];
        dbuf[(size_t)row * 32 + c] = elu(s);
    }
    // student-t q
    float zz = 0.f;
    #pragma unroll
    for (int k = 0; k < 28; k++) zz += zvec[k] * zvec[k];
    float qv[15], qs = 0.f;
    for (int j = 0; j < 15; j++) {
        float cc = 0.f, zc = 0.f;
        for (int k = 0; k < 28; k++) {
            float cv = cluster[j * 28 + k];
            cc += cv * cv; zc += zvec[k] * cv;
        }
        float sq = zz + cc - 2.f * zc;
        if (sq < 0.f) sq = 0.f;
        float qb = 1.f / (1.f + sq * (1.f / 0.9f) + 1e-8f);
        qb = powf(qb, 0.95f);
        qv[j] = qb; qs += qb;
    }
    float qi = 1.f / qs;
    #pragma unroll
    for (int j = 0; j < 15; j++) out_q[(size_t)row * 15 + j] = qv[j] * qi;
}

// ------------- Kernel I: de_feat = d @ out_w + out_b -------------
#define DQ 750   // DIN/4 quads per row
__global__ __launch_bounds__(256) void k_dec_out(
    const float* __restrict__ dbuf, const float* __restrict__ ow,
    const float* __restrict__ ob, float* __restrict__ out_de)
{
    __shared__ float4 wt[32 * 64];   // [k][quad]
    __shared__ float  dt[64 * 32];   // [row][k]
    const int tid = threadIdx.x;
    const int cq0 = blockIdx.x * 64;      // quad base in output row
    const int row0 = blockIdx.y * 64;

    // load w tile: 32 k-rows x 64 quads
    #pragma unroll
    for (int i = 0; i < 8; i++) {
        int t = tid + i * 256;            // 0..2047
        int k = t >> 6, lq = t & 63;
        int gq = cq0 + lq;
        wt[t] = (gq < DQ) ? ((const float4*)ow)[(size_t)k * DQ + gq]
                          : make_float4(0.f, 0.f, 0.f, 0.f);
    }
    // load d tile: 64 rows x 32 = 512 float4
    #pragma unroll
    for (int i = 0; i < 2; i++) {
        int t = tid + i * 256;
        ((float4*)dt)[t] = ((const float4*)dbuf)[(size_t)row0 * 8 + t];
    }
    __syncthreads();

    const int qid = tid & 63;
    const int rg  = tid >> 6;             // wave-uniform row group (0..3)
    const int q   = cq0 + qid;
    const bool valid = q < DQ;

    float4 acc[16];
    #pragma unroll
    for (int r = 0; r < 16; r++) acc[r] = make_float4(0.f, 0.f, 0.f, 0.f);

    #pragma unroll
    for (int k4 = 0; k4 < 8; k4++) {
        float4 w0 = wt[(k4 * 4 + 0) * 64 + qid];
        float4 w1 = wt[(k4 * 4 + 1) * 64 + qid];
        float4 w2 = wt[(k4 * 4 + 2) * 64 + qid];
        float4 w3 = wt[(k4 * 4 + 3) * 64 + qid];
        #pragma unroll
        for (int r = 0; r < 16; r++) {
            float4 dq = *(const float4*)&dt[(rg * 16 + r) * 32 + k4 * 4]; // broadcast
            acc[r].x += dq.x * w0.x; acc[r].y += dq.x * w0.y;
            acc[r].z += dq.x * w0.z; acc[r].w += dq.x * w0.w;
            acc[r].x += dq.y * w1.x; acc[r].y += dq.y * w1.y;
            acc[r].z += dq.y * w1.z; acc[r].w += dq.y * w1.w;
            acc[r].x += dq.z * w2.x; acc[r].y += dq.z * w2.y;
            acc[r].z += dq.z * w2.z; acc[r].w += dq.z * w2.w;
            acc[r].x += dq.w * w3.x; acc[r].y += dq.w * w3.y;
            acc[r].z += dq.w * w3.z; acc[r].w += dq.w * w3.w;
        }
    }

    if (valid) {
        float4 bq = ((const float4*)ob)[q];
        #pragma unroll
        for (int r = 0; r < 16; r++) {
            float4 o;
            o.x = acc[r].x + bq.x; o.y = acc[r].y + bq.y;
            o.z = acc[r].z + bq.z; o.w = acc[r].w + bq.w;
            ((float4*)out_de)[(size_t)(row0 + rg * 16 + r) * DQ + q] = o;
        }
    }
}

extern "C" void kernel_launch(void* const* d_in, const int* in_sizes, int n_in,
                              void* d_out, int out_size, void* d_ws, size_t ws_size,
                              hipStream_t stream) {
    const float* x      = (const float*)d_in[0];
    const int*   ei     = (const int*)  d_in[1];
    const float* e0_w   = (const float*)d_in[2];
    const float* e0_b   = (const float*)d_in[3];
    const float* e0_g   = (const float*)d_in[4];
    const float* e0_be  = (const float*)d_in[5];
    const float* e0_m   = (const float*)d_in[6];
    const float* e0_v   = (const float*)d_in[7];
    const float* e1_w   = (const float*)d_in[8];
    const float* e1_b   = (const float*)d_in[9];
    const float* e1_g   = (const float*)d_in[10];
    const float* e1_be  = (const float*)d_in[11];
    const float* e1_m   = (const float*)d_in[12];
    const float* e1_v   = (const float*)d_in[13];
    const float* g1_w   = (const float*)d_in[14];
    const float* g1_as  = (const float*)d_in[15];
    const float* g1_ad  = (const float*)d_in[16];
    const float* g1_b   = (const float*)d_in[17];
    const float* bnc_g  = (const float*)d_in[18];
    const float* bnc_be = (const float*)d_in[19];
    const float* bnc_m  = (const float*)d_in[20];
    const float* bnc_v  = (const float*)d_in[21];
    const float* gm_w   = (const float*)d_in[22];
    const float* gm_as  = (const float*)d_in[23];
    const float* gm_ad  = (const float*)d_in[24];
    const float* gm_b   = (const float*)d_in[25];
    const float* gv_w   = (const float*)d_in[26];
    const float* gv_as  = (const float*)d_in[27];
    const float* gv_ad  = (const float*)d_in[28];
    const float* gv_b   = (const float*)d_in[29];
    const float* d0_w   = (const float*)d_in[30];
    const float* d0_b   = (const float*)d_in[31];
    const float* d0_g   = (const float*)d_in[32];
    const float* d0_be  = (const float*)d_in[33];
    const float* d0_m   = (const float*)d_in[34];
    const float* d0_v   = (const float*)d_in[35];
    const float* out_w  = (const float*)d_in[36];
    const float* out_b  = (const float*)d_in[37];
    const float* cluster= (const float*)d_in[38];
    const float* epsin  = (const float*)d_in[39];

    float* out = (float*)d_out;
    // output offsets (floats), return order: z, mu, logvar, de_feat, q, feat_x, gnn_z
    float* out_z  = out;
    float* out_mu = out + (size_t)NN * 28;
    float* out_lv = out + (size_t)NN * 36;
    float* out_de = out + (size_t)NN * 44;
    float* out_q  = out + (size_t)NN * 44 + (size_t)NN * DIN;
    float* out_fx = out + (size_t)NN * 59 + (size_t)NN * DIN;
    float* out_gz = out + (size_t)NN * 79 + (size_t)NN * DIN;

    float* ws = (float*)d_ws;
    const size_t n = NN;
    // phase-1 layout
    float* hw1   = ws;                 // 64N
    float* acc1  = ws + 64 * n;        // 64N
    float* hbuf  = ws + 128 * n;       // 32N (h, later reused as dbuf)
    float* s1src = ws + 160 * n;
    float* s1dst = ws + 161 * n;
    float* z1    = ws + 162 * n;
    // phase-2 layout (reuses hw1's 64N block after GAT1 is done)
    float* hwm   = ws;                 // 8N
    float* hwv   = ws + 8 * n;         // 8N
    float* smsrc = ws + 16 * n;
    float* smdst = ws + 17 * n;
    float* svsrc = ws + 18 * n;
    float* svdst = ws + 19 * n;
    float* zm    = ws + 20 * n;
    float* zv    = ws + 21 * n;
    float* accm  = ws + 24 * n;        // 8N
    float* accv  = ws + 32 * n;        // 8N
    float* dbuf  = hbuf;               // 32N

    const int NB_ROWS = (NN + 255) / 256;  // 157

    k_enc0<<<NN / ROWS, 256, 0, stream>>>(x, e0_w, e0_b, e0_g, e0_be, e0_m, e0_v, hbuf);
    k_enc1_prep<<<NB_ROWS, 256, 0, stream>>>(hbuf, e1_w, e1_b, e1_g, e1_be, e1_m, e1_v,
                                             g1_w, g1_as, g1_ad,
                                             out_fx, hw1, s1src, s1dst, z1, acc1);
    k_gat1_acc<<<(ET * 64) / 256, 256, 0, stream>>>(ei, s1src, s1dst, hw1, z1, acc1);
    k_gat1_norm<<<NB_ROWS, 256, 0, stream>>>(acc1, z1, g1_b, bnc_g, bnc_be, bnc_m, bnc_v,
                                             gm_w, gm_as, gm_ad, gv_w, gv_as, gv_ad,
                                             hwm, hwv, smsrc, smdst, svsrc, svdst,
                                             zm, zv, accm, accv);
    k_gat23_acc<<<(ET * 8) / 256, 256, 0, stream>>>(ei, smsrc, smdst, svsrc, svdst,
                                                    hwm, hwv, zm, accm, zv, accv);
    k_final<<<NB_ROWS, 256, 0, stream>>>(accm, zm, gm_b, accv, zv, gv_b, epsin, out_fx,
                                         d0_w, d0_b, d0_g, d0_be, d0_m, d0_v, cluster,
                                         out_z, out_mu, out_lv, out_q, out_gz, dbuf);
    dim3 dec_grid((DQ + 63) / 64, NN / 64);
    k_dec_out<<<dec_grid, 256, 0, stream>>>(dbuf, out_w, out_b, out_de);
}

// Round 9
// 880.683 us; speedup vs baseline: 1.2125x; 1.2117x over previous
//
#include <hip/hip_runtime.h>
#include <cfloat>
#include <cmath>

#define NN 40000
#define DIN 3000
#define NE 640000
#define ET (NE + NN)   // edges incl. self-loops = 680000

#define ROWS 128      // rows per block in k_enc0
#define NCH 5         // split-K chunks
#define KCH 600       // K per chunk
#define KC 40         // K per LDS stage (15 stages/chunk)
#define SXF 44        // x row stride in floats = 11 quads (odd -> conflict-free)

__device__ __forceinline__ float lrelu(float x) { return x >= 0.f ? x : 0.2f * x; }
__device__ __forceinline__ float elu(float x)   { return x > 0.f ? x : expm1f(x); }

// ---------------- Kernel A: partial = x @ e0_w (split-K x5) ----------------
// Block 128 thr = 128 rows x 32 cols; thread = 4 rows (stride 32) x 8 cols:
// acc[4][2] float4 = 32 VGPR, LDS traffic 1.5 B/MAC (w reads broadcast-free).
// Sync staging (short-lived regs only -> no spill); TLP (5 blocks/CU) hides
// stage latency. x row-quad-stride 11 (odd): 16 rows/instr -> 2-way max = free.
__global__ void k_enc0(
    const float* __restrict__ x, const float* __restrict__ w,
    float* __restrict__ partial)   // [NCH][NN][32]
{
    __shared__ float xt[ROWS * SXF];   // 22.5 KB
    __shared__ float wt[KC * 32];      // 5 KB
    const int tid = threadIdx.x;       // 0..127
    const int cg = tid & 3;            // col group (8 cols)
    const int rg = tid >> 2;           // 0..31
    const int row0 = blockIdx.x * ROWS;
    const int kb = blockIdx.y * KCH;

    float4 acc[4][2];
    #pragma unroll
    for (int r = 0; r < 4; r++) {
        acc[r][0] = make_float4(0.f, 0.f, 0.f, 0.f);
        acc[r][1] = make_float4(0.f, 0.f, 0.f, 0.f);
    }

    for (int ch = 0; ch < KCH / KC; ch++) {
        const int kc = kb + ch * KC;
        __syncthreads();
        // stage x: 128 rows x 10 quads = 1280 quads
        for (int j = tid; j < 1280; j += 128) {
            int r = j / 10, q = j - r * 10;
            int grow = row0 + r; if (grow > NN - 1) grow = NN - 1;
            float4 vx = *(const float4*)&x[(size_t)grow * DIN + kc + q * 4];
            *(float4*)&xt[r * SXF + q * 4] = vx;
        }
        // stage w: 40x32 = 320 contiguous quads
        for (int j = tid; j < 320; j += 128)
            ((float4*)wt)[j] = ((const float4*)&w[(size_t)kc * 32])[j];
        __syncthreads();

        #pragma unroll
        for (int s = 0; s < KC / 4; s++) {
            float4 xa0 = *(const float4*)&xt[(rg     ) * SXF + s * 4];
            float4 xa1 = *(const float4*)&xt[(rg + 32) * SXF + s * 4];
            float4 xa2 = *(const float4*)&xt[(rg + 64) * SXF + s * 4];
            float4 xa3 = *(const float4*)&xt[(rg + 96) * SXF + s * 4];
            #pragma unroll
            for (int i = 0; i < 4; i++) {
                float4 w0 = *(const float4*)&wt[(s * 4 + i) * 32 + cg * 8];
                float4 w1 = *(const float4*)&wt[(s * 4 + i) * 32 + cg * 8 + 4];
                float xs0 = (i == 0) ? xa0.x : (i == 1) ? xa0.y : (i == 2) ? xa0.z : xa0.w;
                float xs1 = (i == 0) ? xa1.x : (i == 1) ? xa1.y : (i == 2) ? xa1.z : xa1.w;
                float xs2 = (i == 0) ? xa2.x : (i == 1) ? xa2.y : (i == 2) ? xa2.z : xa2.w;
                float xs3 = (i == 0) ? xa3.x : (i == 1) ? xa3.y : (i == 2) ? xa3.z : xa3.w;
                acc[0][0].x += xs0 * w0.x; acc[0][0].y += xs0 * w0.y;
                acc[0][0].z += xs0 * w0.z; acc[0][0].w += xs0 * w0.w;
                acc[0][1].x += xs0 * w1.x; acc[0][1].y += xs0 * w1.y;
                acc[0][1].z += xs0 * w1.z; acc[0][1].w += xs0 * w1.w;
                acc[1][0].x += xs1 * w0.x; acc[1][0].y += xs1 * w0.y;
                acc[1][0].z += xs1 * w0.z; acc[1][0].w += xs1 * w0.w;
                acc[1][1].x += xs1 * w1.x; acc[1][1].y += xs1 * w1.y;
                acc[1][1].z += xs1 * w1.z; acc[1][1].w += xs1 * w1.w;
                acc[2][0].x += xs2 * w0.x; acc[2][0].y += xs2 * w0.y;
                acc[2][0].z += xs2 * w0.z; acc[2][0].w += xs2 * w0.w;
                acc[2][1].x += xs2 * w1.x; acc[2][1].y += xs2 * w1.y;
                acc[2][1].z += xs2 * w1.z; acc[2][1].w += xs2 * w1.w;
                acc[3][0].x += xs3 * w0.x; acc[3][0].y += xs3 * w0.y;
                acc[3][0].z += xs3 * w0.z; acc[3][0].w += xs3 * w0.w;
                acc[3][1].x += xs3 * w1.x; acc[3][1].y += xs3 * w1.y;
                acc[3][1].z += xs3 * w1.z; acc[3][1].w += xs3 * w1.w;
            }
        }
    }

    #pragma unroll
    for (int rr = 0; rr < 4; rr++) {
        int row = row0 + rg + 32 * rr;
        if (row < NN) {
            size_t o = ((size_t)blockIdx.y * NN + row) * 32 + cg * 8;
            *(float4*)&partial[o]     = acc[rr][0];
            *(float4*)&partial[o + 4] = acc[rr][1];
        }
    }
}

// ------- Kernel A2: h = elu(bn(sum partials + e0_b)) -------
// h aliases partial chunk 4; each thread reads its own quad then overwrites -> safe.
__global__ void k_enc0_fin(
    const float* __restrict__ partial,
    const float* __restrict__ b, const float* __restrict__ g,
    const float* __restrict__ beta, const float* __restrict__ m,
    const float* __restrict__ v, float* __restrict__ h)
{
    int q = blockIdx.x * 256 + threadIdx.x;   // quad index over [NN*8)
    if (q >= NN * 8) return;
    int c = (q & 7) * 4;
    float4 s = make_float4(0.f, 0.f, 0.f, 0.f);
    #pragma unroll
    for (int ch = 0; ch < NCH; ch++) {
        float4 p = ((const float4*)partial)[(size_t)ch * NN * 8 + q];
        s.x += p.x; s.y += p.y; s.z += p.z; s.w += p.w;
    }
    float sc0 = g[c+0] * rsqrtf(v[c+0] + 1e-3f);
    float sc1 = g[c+1] * rsqrtf(v[c+1] + 1e-3f);
    float sc2 = g[c+2] * rsqrtf(v[c+2] + 1e-3f);
    float sc3 = g[c+3] * rsqrtf(v[c+3] + 1e-3f);
    float4 o;
    o.x = elu((s.x + b[c+0]) * sc0 + (beta[c+0] - m[c+0] * sc0));
    o.y = elu((s.y + b[c+1]) * sc1 + (beta[c+1] - m[c+1] * sc1));
    o.z = elu((s.z + b[c+2]) * sc2 + (beta[c+2] - m[c+2] * sc2));
    o.w = elu((s.w + b[c+3]) * sc3 + (beta[c+3] - m[c+3] * sc3));
    ((float4*)h)[q] = o;
}

// ------------- Kernel B: feat_x, hw1, attention scalars, init GAT1 atomics -------------
__global__ void k_enc1_prep(
    const float* __restrict__ h,
    const float* __restrict__ e1w, const float* __restrict__ e1b,
    const float* __restrict__ e1g, const float* __restrict__ e1beta,
    const float* __restrict__ e1m, const float* __restrict__ e1v,
    const float* __restrict__ g1w, const float* __restrict__ g1as,
    const float* __restrict__ g1ad,
    float* __restrict__ out_fx, float* __restrict__ hw1,
    float* __restrict__ s1src, float* __restrict__ s1dst,
    float* __restrict__ z1, float* __restrict__ acc1)
{
    int row = blockIdx.x * 256 + threadIdx.x;
    if (row >= NN) return;
    float hr[32];
    #pragma unroll
    for (int k = 0; k < 32; k++) hr[k] = h[(size_t)row * 32 + k];
    float fx[20];
    for (int c = 0; c < 20; c++) {
        float s = e1b[c];
        for (int k = 0; k < 32; k++) s += hr[k] * e1w[k * 20 + c];
        float sc = e1g[c] * rsqrtf(e1v[c] + 1e-3f);
        s = (s - e1m[c]) * sc + e1beta[c];
        fx[c] = elu(s);
        out_fx[(size_t)row * 20 + c] = fx[c];
    }
    float ss = 0.f, sd = 0.f;
    for (int c = 0; c < 64; c++) {
        float s = 0.f;
        for (int k = 0; k < 20; k++) s += fx[k] * g1w[k * 64 + c];
        hw1[(size_t)row * 64 + c] = s;
        ss += s * g1as[c];
        sd += s * g1ad[c];
        acc1[(size_t)row * 64 + c] = 0.f;
    }
    s1src[row] = ss; s1dst[row] = sd;
    z1[row] = 0.f;
}

// ------------- Kernel D: GAT1 numerator/denominator accumulate (64 lanes/edge) -------------
// softmax is shift-invariant: use exp(al) directly (logits bounded ~|3|), skip max pass.
__global__ __launch_bounds__(256) void k_gat1_acc(const int* __restrict__ ei,
    const float* __restrict__ s1src, const float* __restrict__ s1dst,
    const float* __restrict__ hw1,
    float* __restrict__ z1, float* __restrict__ acc1)
{
    int t = blockIdx.x * 256 + threadIdx.x;
    int lane = t & 63;
    int e = t >> 6;
    if (e >= ET) return;
    int s, d;
    if (e < NE) { s = ei[e]; d = ei[NE + e]; } else { s = d = e - NE; }
    float al = lrelu(s1src[s] + s1dst[d]);
    float ex = expf(al);
    if (lane == 0) atomicAdd(&z1[d], ex);
    atomicAdd(&acc1[(size_t)d * 64 + lane], ex * hw1[(size_t)s * 64 + lane]);
}

// ------------- Kernel E: normalize GAT1, BN+ReLU -> c; hw_m/hw_v + scalars; init atomics -------------
__global__ void k_gat1_norm(
    const float* __restrict__ acc1, const float* __restrict__ z1,
    const float* __restrict__ g1b,
    const float* __restrict__ bncg, const float* __restrict__ bncbeta,
    const float* __restrict__ bncm, const float* __restrict__ bncv,
    const float* __restrict__ gmw, const float* __restrict__ gmas, const float* __restrict__ gmad,
    const float* __restrict__ gvw, const float* __restrict__ gvas, const float* __restrict__ gvad,
    float* __restrict__ hwm, float* __restrict__ hwv,
    float* __restrict__ smsrc, float* __restrict__ smdst,
    float* __restrict__ svsrc, float* __restrict__ svdst,
    float* __restrict__ zm, float* __restrict__ zv,
    float* __restrict__ accm, float* __restrict__ accv)
{
    int row = blockIdx.x * 256 + threadIdx.x;
    if (row >= NN) return;
    float zi = 1.f / (z1[row] + 1e-16f);
    float c[64];
    for (int f = 0; f < 64; f++) {
        float val = acc1[(size_t)row * 64 + f] * zi + g1b[f];
        float sc = bncg[f] * rsqrtf(bncv[f] + 1e-5f);
        val = (val - bncm[f]) * sc + bncbeta[f];
        c[f] = val > 0.f ? val : 0.f;
    }
    float ssm = 0.f, sdm = 0.f, ssv = 0.f, sdv = 0.f;
    for (int o = 0; o < 8; o++) {
        float sm = 0.f, sv = 0.f;
        for (int k = 0; k < 64; k++) {
            sm += c[k] * gmw[k * 8 + o];
            sv += c[k] * gvw[k * 8 + o];
        }
        hwm[(size_t)row * 8 + o] = sm; hwv[(size_t)row * 8 + o] = sv;
        ssm += sm * gmas[o]; sdm += sm * gmad[o];
        ssv += sv * gvas[o]; sdv += sv * gvad[o];
        accm[(size_t)row * 8 + o] = 0.f; accv[(size_t)row * 8 + o] = 0.f;
    }
    smsrc[row] = ssm; smdst[row] = sdm;
    svsrc[row] = ssv; svdst[row] = sdv;
    zm[row] = 0.f;
    zv[row] = 0.f;
}

// ------------- Kernel G: mu/logvar GAT accumulate (8 lanes/edge), no max pass -------------
__global__ __launch_bounds__(256) void k_gat23_acc(const int* __restrict__ ei,
    const float* __restrict__ smsrc, const float* __restrict__ smdst,
    const float* __restrict__ svsrc, const float* __restrict__ svdst,
    const float* __restrict__ hwm, const float* __restrict__ hwv,
    float* __restrict__ zm, float* __restrict__ accm,
    float* __restrict__ zv, float* __restrict__ accv)
{
    int t = blockIdx.x * 256 + threadIdx.x;
    int lane = t & 7;
    int e = t >> 3;
    if (e >= ET) return;
    int s, d;
    if (e < NE) { s = ei[e]; d = ei[NE + e]; } else { s = d = e - NE; }
    float am = lrelu(smsrc[s] + smdst[d]);
    float exm = expf(am);
    if (lane == 0) atomicAdd(&zm[d], exm);
    atomicAdd(&accm[(size_t)d * 8 + lane], exm * hwm[(size_t)s * 8 + lane]);
    float av = lrelu(svsrc[s] + svdst[d]);
    float exv = expf(av);
    if (lane == 0) atomicAdd(&zv[d], exv);
    atomicAdd(&accv[(size_t)d * 8 + lane], exv * hwv[(size_t)s * 8 + lane]);
}

// ------------- Kernel H: mu/logvar/gnn_z/z, decoder L0, student-t q -------------
__global__ void k_final(
    const float* __restrict__ accm, const float* __restrict__ zm, const float* __restrict__ gmb,
    const float* __restrict__ accv, const float* __restrict__ zv, const float* __restrict__ gvb,
    const float* __restrict__ epsin, const float* __restrict__ fx_out,
    const float* __restrict__ d0w, const float* __restrict__ d0b,
    const float* __restrict__ d0g, const float* __restrict__ d0beta,
    const float* __restrict__ d0m, const float* __restrict__ d0v,
    const float* __restrict__ cluster,
    float* __restrict__ out_z, float* __restrict__ out_mu, float* __restrict__ out_lv,
    float* __restrict__ out_q, float* __restrict__ out_gz, float* __restrict__ dbuf)
{
    int row = blockIdx.x * 256 + threadIdx.x;
    if (row >= NN) return;
    float zvec[28];
    #pragma unroll
    for (int k = 0; k < 20; k++) zvec[k] = fx_out[(size_t)row * 20 + k];
    float zim = 1.f / (zm[row] + 1e-16f);
    float ziv = 1.f / (zv[row] + 1e-16f);
    #pragma unroll
    for (int o = 0; o < 8; o++) {
        float mu = accm[(size_t)row * 8 + o] * zim + gmb[o];
        float lv = accv[(size_t)row * 8 + o] * ziv + gvb[o];
        float gz = epsin[(size_t)row * 8 + o] * expf(lv) + mu;
        out_mu[(size_t)row * 8 + o] = mu;
        out_lv[(size_t)row * 8 + o] = lv;
        out_gz[(size_t)row * 8 + o] = gz;
        zvec[20 + o] = gz;
    }
    #pragma unroll
    for (int k = 0; k < 28; k++) out_z[(size_t)row * 28 + k] = zvec[k];
    // decoder L0: elu(bn(z @ d0_w + d0_b))
    for (int c = 0; c < 32; c++) {
        float s = d0b[c];
        for (int k = 0; k < 28; k++) s += zvec[k] * d0w[k * 32 + c];
        float sc = d0g[c] * rsqrtf(d0v[c] + 1e-3f);
        s = (s - d0m[c]) * sc + d0beta[c];
        dbuf[(size_t)row * 32 + c] = elu(s);
    }
    // student-t q
    float zz = 0.f;
    #pragma unroll
    for (int k = 0; k < 28; k++) zz += zvec[k] * zvec[k];
    float qv[15], qs = 0.f;
    for (int j = 0; j < 15; j++) {
        float cc = 0.f, zc = 0.f;
        for (int k = 0; k < 28; k++) {
            float cv = cluster[j * 28 + k];
            cc += cv * cv; zc += zvec[k] * cv;
        }
        float sq = zz + cc - 2.f * zc;
        if (sq < 0.f) sq = 0.f;
        float qb = 1.f / (1.f + sq * (1.f / 0.9f) + 1e-8f);
        qb = powf(qb, 0.95f);
        qv[j] = qb; qs += qb;
    }
    float qi = 1.f / qs;
    #pragma unroll
    for (int j = 0; j < 15; j++) out_q[(size_t)row * 15 + j] = qv[j] * qi;
}

// ------------- Kernel I: de_feat = d @ out_w + out_b -------------
#define DQ 750   // DIN/4 quads per row
__global__ __launch_bounds__(256) void k_dec_out(
    const float* __restrict__ dbuf, const float* __restrict__ ow,
    const float* __restrict__ ob, float* __restrict__ out_de)
{
    __shared__ float4 wt[32 * 64];   // [k][quad]
    __shared__ float  dt[64 * 32];   // [row][k]
    const int tid = threadIdx.x;
    const int cq0 = blockIdx.x * 64;      // quad base in output row
    const int row0 = blockIdx.y * 64;

    // load w tile: 32 k-rows x 64 quads
    #pragma unroll
    for (int i = 0; i < 8; i++) {
        int t = tid + i * 256;            // 0..2047
        int k = t >> 6, lq = t & 63;
        int gq = cq0 + lq;
        wt[t] = (gq < DQ) ? ((const float4*)ow)[(size_t)k * DQ + gq]
                          : make_float4(0.f, 0.f, 0.f, 0.f);
    }
    // load d tile: 64 rows x 32 = 512 float4
    #pragma unroll
    for (int i = 0; i < 2; i++) {
        int t = tid + i * 256;
        ((float4*)dt)[t] = ((const float4*)dbuf)[(size_t)row0 * 8 + t];
    }
    __syncthreads();

    const int qid = tid & 63;
    const int rg  = tid >> 6;             // wave-uniform row group (0..3)
    const int q   = cq0 + qid;
    const bool valid = q < DQ;

    float4 acc[16];
    #pragma unroll
    for (int r = 0; r < 16; r++) acc[r] = make_float4(0.f, 0.f, 0.f, 0.f);

    #pragma unroll
    for (int k4 = 0; k4 < 8; k4++) {
        float4 w0 = wt[(k4 * 4 + 0) * 64 + qid];
        float4 w1 = wt[(k4 * 4 + 1) * 64 + qid];
        float4 w2 = wt[(k4 * 4 + 2) * 64 + qid];
        float4 w3 = wt[(k4 * 4 + 3) * 64 + qid];
        #pragma unroll
        for (int r = 0; r < 16; r++) {
            float4 dq = *(const float4*)&dt[(rg * 16 + r) * 32 + k4 * 4]; // broadcast
            acc[r].x += dq.x * w0.x; acc[r].y += dq.x * w0.y;
            acc[r].z += dq.x * w0.z; acc[r].w += dq.x * w0.w;
            acc[r].x += dq.y * w1.x; acc[r].y += dq.y * w1.y;
            acc[r].z += dq.y * w1.z; acc[r].w += dq.y * w1.w;
            acc[r].x += dq.z * w2.x; acc[r].y += dq.z * w2.y;
            acc[r].z += dq.z * w2.z; acc[r].w += dq.z * w2.w;
            acc[r].x += dq.w * w3.x; acc[r].y += dq.w * w3.y;
            acc[r].z += dq.w * w3.z; acc[r].w += dq.w * w3.w;
        }
    }

    if (valid) {
        float4 bq = ((const float4*)ob)[q];
        #pragma unroll
        for (int r = 0; r < 16; r++) {
            float4 o;
            o.x = acc[r].x + bq.x; o.y = acc[r].y + bq.y;
            o.z = acc[r].z + bq.z; o.w = acc[r].w + bq.w;
            ((float4*)out_de)[(size_t)(row0 + rg * 16 + r) * DQ + q] = o;
        }
    }
}

extern "C" void kernel_launch(void* const* d_in, const int* in_sizes, int n_in,
                              void* d_out, int out_size, void* d_ws, size_t ws_size,
                              hipStream_t stream) {
    const float* x      = (const float*)d_in[0];
    const int*   ei     = (const int*)  d_in[1];
    const float* e0_w   = (const float*)d_in[2];
    const float* e0_b   = (const float*)d_in[3];
    const float* e0_g   = (const float*)d_in[4];
    const float* e0_be  = (const float*)d_in[5];
    const float* e0_m   = (const float*)d_in[6];
    const float* e0_v   = (const float*)d_in[7];
    const float* e1_w   = (const float*)d_in[8];
    const float* e1_b   = (const float*)d_in[9];
    const float* e1_g   = (const float*)d_in[10];
    const float* e1_be  = (const float*)d_in[11];
    const float* e1_m   = (const float*)d_in[12];
    const float* e1_v   = (const float*)d_in[13];
    const float* g1_w   = (const float*)d_in[14];
    const float* g1_as  = (const float*)d_in[15];
    const float* g1_ad  = (const float*)d_in[16];
    const float* g1_b   = (const float*)d_in[17];
    const float* bnc_g  = (const float*)d_in[18];
    const float* bnc_be = (const float*)d_in[19];
    const float* bnc_m  = (const float*)d_in[20];
    const float* bnc_v  = (const float*)d_in[21];
    const float* gm_w   = (const float*)d_in[22];
    const float* gm_as  = (const float*)d_in[23];
    const float* gm_ad  = (const float*)d_in[24];
    const float* gm_b   = (const float*)d_in[25];
    const float* gv_w   = (const float*)d_in[26];
    const float* gv_as  = (const float*)d_in[27];
    const float* gv_ad  = (const float*)d_in[28];
    const float* gv_b   = (const float*)d_in[29];
    const float* d0_w   = (const float*)d_in[30];
    const float* d0_b   = (const float*)d_in[31];
    const float* d0_g   = (const float*)d_in[32];
    const float* d0_be  = (const float*)d_in[33];
    const float* d0_m   = (const float*)d_in[34];
    const float* d0_v   = (const float*)d_in[35];
    const float* out_w  = (const float*)d_in[36];
    const float* out_b  = (const float*)d_in[37];
    const float* cluster= (const float*)d_in[38];
    const float* epsin  = (const float*)d_in[39];

    float* out = (float*)d_out;
    // output offsets (floats), return order: z, mu, logvar, de_feat, q, feat_x, gnn_z
    float* out_z  = out;
    float* out_mu = out + (size_t)NN * 28;
    float* out_lv = out + (size_t)NN * 36;
    float* out_de = out + (size_t)NN * 44;
    float* out_q  = out + (size_t)NN * 44 + (size_t)NN * DIN;
    float* out_fx = out + (size_t)NN * 59 + (size_t)NN * DIN;
    float* out_gz = out + (size_t)NN * 79 + (size_t)NN * DIN;

    float* ws = (float*)d_ws;
    const size_t n = NN;
    // enc0: partial[5][N][32] = ws[0..160N); chunk-4 slice aliases hbuf.
    float* partial = ws;
    // phase-1 layout
    float* hw1   = ws;                 // 64N
    float* acc1  = ws + 64 * n;        // 64N
    float* hbuf  = ws + 128 * n;       // 32N (h, later reused as dbuf)
    float* s1src = ws + 160 * n;
    float* s1dst = ws + 161 * n;
    float* z1    = ws + 162 * n;
    // phase-2 layout (reuses hw1's 64N block after GAT1 is done)
    float* hwm   = ws;                 // 8N
    float* hwv   = ws + 8 * n;         // 8N
    float* smsrc = ws + 16 * n;
    float* smdst = ws + 17 * n;
    float* svsrc = ws + 18 * n;
    float* svdst = ws + 19 * n;
    float* zm    = ws + 20 * n;
    float* zv    = ws + 21 * n;
    float* accm  = ws + 24 * n;        // 8N
    float* accv  = ws + 32 * n;        // 8N
    float* dbuf  = hbuf;               // 32N

    const int NB_ROWS = (NN + 255) / 256;  // 157

    dim3 enc0_grid((NN + ROWS - 1) / ROWS, NCH);   // 313 x 5
    k_enc0<<<enc0_grid, 128, 0, stream>>>(x, e0_w, partial);
    k_enc0_fin<<<(NN * 8 + 255) / 256, 256, 0, stream>>>(partial, e0_b, e0_g, e0_be,
                                                         e0_m, e0_v, hbuf);
    k_enc1_prep<<<NB_ROWS, 256, 0, stream>>>(hbuf, e1_w, e1_b, e1_g, e1_be, e1_m, e1_v,
                                             g1_w, g1_as, g1_ad,
                                             out_fx, hw1, s1src, s1dst, z1, acc1);
    k_gat1_acc<<<(ET * 64) / 256, 256, 0, stream>>>(ei, s1src, s1dst, hw1, z1, acc1);
    k_gat1_norm<<<NB_ROWS, 256, 0, stream>>>(acc1, z1, g1_b, bnc_g, bnc_be, bnc_m, bnc_v,
                                             gm_w, gm_as, gm_ad, gv_w, gv_as, gv_ad,
                                             hwm, hwv, smsrc, smdst, svsrc, svdst,
                                             zm, zv, accm, accv);
    k_gat23_acc<<<(ET * 8) / 256, 256, 0, stream>>>(ei, smsrc, smdst, svsrc, svdst,
                                                    hwm, hwv, zm, accm, zv, accv);
    k_final<<<NB_ROWS, 256, 0, stream>>>(accm, zm, gm_b, accv, zv, gv_b, epsin, out_fx,
                                         d0_w, d0_b, d0_g, d0_be, d0_m, d0_v, cluster,
                                         out_z, out_mu, out_lv, out_q, out_gz, dbuf);
    dim3 dec_grid((DQ + 63) / 64, NN / 64);
    k_dec_out<<<dec_grid, 256, 0, stream>>>(dbuf, out_w, out_b, out_de);
}